// Round 12
// baseline (207.806 us; speedup 1.0000x reference)
//
#include <hip/hip_runtime.h>
#include <stdint.h>

#define NIMG 32
#define CH 32
#define HH 160
#define WW 160
#define HWL (HH*WW)            // 25600
#define PRS 164                // padded row stride (words)
#define PHH 162
#define PIMG (PHH*PRS)         // 26568 words per padded image
#define NPIX (NIMG*HWL)        // 819200 pixels
#define HALO_WORDS 968         // per image: 2*164 + 160*4

// workspace layout (bytes)
#define OFF_P     0
#define OFF_P2    3400704                    // P : 32*26568*4
#define OFF_Y1    (OFF_P2 + 3400704)         // P2: same
#define OFF_Y2    (OFF_Y1 + 52428800)        // Y1: int16
#define OFF_WP    (OFF_Y2 + 52428800)        // Y2: int16
#define OFF_CORR  (OFF_WP + 2304)
#define OFF_SC    (OFF_CORR + 2304)
#define OFF_SB    (OFF_SC + 128)             // 64 StatLines x 128 B

struct StatLine {                            // one 128B line per channel
  int s1; int pad0; unsigned long long s2; char pad[112];
};

#define AS1 __attribute__((address_space(1)))
#define AS3 __attribute__((address_space(3)))
__device__ __forceinline__ void dma16(const void* g, void* l) {
  __builtin_amdgcn_global_load_lds((const AS1 void*)g, (AS3 void*)l, 16, 0, 0);
}

__device__ __forceinline__ void conv4(const uint32_t r[3][6], const uint32_t* wsh,
                                      int co, int& a0, int& a1, int& a2, int& a3)
{
  a0 = a1 = a2 = a3 = 0;
  #pragma unroll
  for (int dy = 0; dy < 3; ++dy) {
    #pragma unroll
    for (int dx = 0; dx < 3; ++dx) {
      uint32_t wvv = wsh[co * 9 + dy * 3 + dx];
      a0 += __popc(r[dy][0 + dx] ^ wvv);
      a1 += __popc(r[dy][1 + dx] ^ wvv);
      a2 += __popc(r[dy][2 + dx] ^ wvv);
      a3 += __popc(r[dy][3 + dx] ^ wvv);
    }
  }
}

// fold BN affine (identical math everywhere -> bit-identical A,B)
__device__ __forceinline__ void bn_affine(const float* SCp, const StatLine* sb,
    const float* gamma, const float* beta, int c, float& A, float& B)
{
  double sc = (double)SCp[0];
  double m  = sc * (double)sb[c].s1 / (double)NPIX;
  double ms = sc * sc * (double)(long long)sb[c].s2 / (double)NPIX;
  float inv = (float)(1.0 / sqrt(ms - m * m + 1e-5));
  float gm = gamma[c];
  A = gm * inv * (float)sc;
  B = beta[c] - gm * inv * (float)m;
}

// ================ K1: pack x via LDS DMA staging (256px tile) + prep + halo zero ====
// blocks 0..3199: pack; 3200..3441: halo zero; 3442: prep
__global__ __launch_bounds__(256) void pack_prep(const float* __restrict__ x,
    const float* __restrict__ w1, const float* __restrict__ w2,
    uint32_t* __restrict__ P, uint32_t* __restrict__ P2, uint32_t* __restrict__ WP,
    int* __restrict__ CORR, float* __restrict__ SC, StatLine* __restrict__ SB)
{
  __shared__ float lds[8192];                // 32 KB
  const int tid = threadIdx.x;
  const int b = blockIdx.x;

  if (b >= 3200) {
    if (b == 3442) {
      int* z = (int*)SB;
      for (int i = tid; i < 2048; i += 256) z[i] = 0;
      float* red = lds;
      uint32_t* wpl = (uint32_t*)(lds + 256);
      for (int cv = 0; cv < 2; ++cv) {
        const float* w = cv ? w2 : w1;
        float s = 0.f;
        #pragma unroll
        for (int j = 0; j < 9; ++j) {
          float4 v = *reinterpret_cast<const float4*>(w + (j * 256 + tid) * 4);
          s += fabsf(v.x) + fabsf(v.y) + fabsf(v.z) + fabsf(v.w);
        }
        red[tid] = s;
        __syncthreads();
        for (int st = 128; st > 0; st >>= 1) {
          if (tid < st) red[tid] += red[tid + st];
          __syncthreads();
        }
        if (tid == 0) SC[cv] = red[0] / 9216.0f;
        for (int i = tid; i < 288; i += 256) {
          int co = i / 9, t = i - co * 9;
          uint32_t bw = 0;
          for (int ci = 0; ci < 32; ++ci)
            bw |= (w[(co * 32 + ci) * 9 + t] > 0.0f) ? (1u << ci) : 0u;
          WP[cv * 288 + i] = bw;
          wpl[i] = bw;
        }
        __syncthreads();
        for (int i = tid; i < 288; i += 256) {
          int cls = i / 32, co = i - cls * 32;
          int hc = cls / 3, wc = cls - hc * 3;
          int corr = 0;
          for (int t = 0; t < 9; ++t) {
            int dy = t / 3 - 1, dx = t % 3 - 1;
            bool inval = (hc == 0 && dy == -1) || (hc == 2 && dy == 1) ||
                         (wc == 0 && dx == -1) || (wc == 2 && dx == 1);
            if (inval) corr += 32 - 2 * __popc(wpl[co * 9 + t]);
          }
          CORR[cv * 288 + cls * 32 + co] = corr;
        }
        __syncthreads();
      }
    } else {
      int k = (b - 3200) * 256 + tid;
      uint32_t* buf = (k < 32 * HALO_WORDS) ? P : P2;
      int j = k % (32 * HALO_WORDS);
      int img = j / HALO_WORDS;
      int r = j - img * HALO_WORDS;
      int pr, pc;
      if (r < 164)      { pr = 0;   pc = r; }
      else if (r < 328) { pr = 161; pc = r - 164; }
      else {
        int k2 = r - 328;
        pr = 1 + (k2 >> 2);
        int q = k2 & 3;
        pc = (q == 0) ? 0 : (160 + q);
      }
      buf[img * PIMG + pr * PRS + pc] = 0;
    }
    return;
  }

  int n = b / 100;
  int p0 = (b - n * 100) * 256;
  const float* xb = x + (size_t)n * CH * HWL + p0;
  #pragma unroll
  for (int it = 0; it < 8; ++it) {
    int c = it * 4 + (tid >> 6);
    dma16(xb + (size_t)c * HWL + (tid & 63) * 4, lds + c * 256);
  }
  __syncthreads();

  uint32_t bits = 0;
  #pragma unroll
  for (int c = 0; c < 32; ++c) {
    if (lds[c * 256 + tid] > 0.f) bits |= 1u << c;
  }
  int px = p0 + tid;
  int h = px / WW, w = px - h * WW;
  P[n * PIMG + (h + 1) * PRS + (w + 1)] = bits;
}

// ================ K2/K4: conv -> Y int16 + fused per-channel stats =================
__global__ __launch_bounds__(256) void conv_stats_y(const uint32_t* __restrict__ P,
    const uint32_t* __restrict__ WP, const int* __restrict__ CORR,
    short* __restrict__ Y, StatLine* __restrict__ sb)
{
  __shared__ uint32_t wsh[288];
  __shared__ int csh[288];
  __shared__ int ls1[32], ls2[32];
  const int tid = threadIdx.x;
  for (int i = tid; i < 288; i += 256) { wsh[i] = WP[i]; csh[i] = CORR[i]; }
  if (tid < 32) { ls1[tid] = 0; ls2[tid] = 0; }
  __syncthreads();

  int g = blockIdx.x * 256 + tid;
  int w4 = g % 40;
  int t1 = g / 40;
  int h = t1 % 160;
  int n = t1 / 160;

  const uint32_t* base = P + n * PIMG + h * PRS + w4 * 4;
  uint32_t r[3][6];
  #pragma unroll
  for (int dy = 0; dy < 3; ++dy) {
    uint4 a = *reinterpret_cast<const uint4*>(base + dy * PRS);
    uint2 bw = *reinterpret_cast<const uint2*>(base + dy * PRS + 4);
    r[dy][0] = a.x; r[dy][1] = a.y; r[dy][2] = a.z; r[dy][3] = a.w;
    r[dy][4] = bw.x; r[dy][5] = bw.y;
  }

  int rowc = (h == 0) ? 0 : ((h == 159) ? 6 : 3);
  int cls0  = rowc + ((w4 == 0) ? 0 : 1);
  int cls12 = rowc + 1;
  int cls3  = rowc + ((w4 == 39) ? 2 : 1);
  int lane = tid & 63;

  short* yb = Y + (size_t)n * CH * HWL + h * WW + w4 * 4;

  #pragma unroll
  for (int co = 0; co < 32; ++co) {
    int a0, a1, a2, a3;
    conv4(r, wsh, co, a0, a1, a2, a3);
    int d0 = 288 - 2 * a0 - csh[cls0 * 32 + co];
    int d1 = 288 - 2 * a1 - csh[cls12 * 32 + co];
    int d2 = 288 - 2 * a2 - csh[cls12 * 32 + co];
    int d3 = 288 - 2 * a3 - csh[cls3 * 32 + co];
    *reinterpret_cast<short4*>(yb + (size_t)co * HWL) =
        make_short4((short)d0, (short)d1, (short)d2, (short)d3);
    int ds = d0 + d1 + d2 + d3;
    int sq = d0 * d0 + d1 * d1 + d2 * d2 + d3 * d3;
    #pragma unroll
    for (int off = 32; off > 0; off >>= 1) {
      ds += __shfl_down(ds, off);
      sq += __shfl_down(sq, off);
    }
    if (lane == 0) { atomicAdd(&ls1[co], ds); atomicAdd(&ls2[co], sq); }
  }
  __syncthreads();
  if (tid < 32) {
    atomicAdd(&sb[tid].s1, ls1[tid]);
    atomicAdd(&sb[tid].s2, (unsigned long long)(long long)ls2[tid]);
  }
}

// ================ K3: bits2 = sign(A1*Y1 + B1 + x) -> P2 (no conv) =================
__global__ __launch_bounds__(256, 2) void bits2(const short* __restrict__ Y1,
    const float* __restrict__ x, const float* __restrict__ SCp,
    const StatLine* __restrict__ sb, const float* __restrict__ gamma,
    const float* __restrict__ beta, uint32_t* __restrict__ P2)
{
  __shared__ float Ash[32], Bsh[32];
  const int tid = threadIdx.x;
  if (tid < 32) bn_affine(SCp, sb, gamma, beta, tid, Ash[tid], Bsh[tid]);
  __syncthreads();

  int g = blockIdx.x * 256 + tid;
  int w4 = g % 40;
  int t1 = g / 40;
  int h = t1 % 160;
  int n = t1 / 160;
  int i = h * WW + w4 * 4;
  size_t pbase = (size_t)n * CH * HWL + i;

  uint32_t bb0 = 0, bb1 = 0, bb2 = 0, bb3 = 0;
  #pragma unroll
  for (int cg = 0; cg < 4; ++cg) {
    float4 xv[8];
    short4 yv[8];
    #pragma unroll
    for (int j = 0; j < 8; ++j) {
      size_t idx = pbase + (size_t)(cg * 8 + j) * HWL;
      xv[j] = *reinterpret_cast<const float4*>(x + idx);
      yv[j] = *reinterpret_cast<const short4*>(Y1 + idx);
    }
    #pragma unroll
    for (int j = 0; j < 8; ++j) {
      int co = cg * 8 + j;
      float A = Ash[co], Bv = Bsh[co];
      float v0 = fmaf(A, (float)yv[j].x, Bv) + xv[j].x;
      float v1 = fmaf(A, (float)yv[j].y, Bv) + xv[j].y;
      float v2 = fmaf(A, (float)yv[j].z, Bv) + xv[j].z;
      float v3 = fmaf(A, (float)yv[j].w, Bv) + xv[j].w;
      uint32_t m = 1u << co;
      if (v0 > 0.f) bb0 |= m;
      if (v1 > 0.f) bb1 |= m;
      if (v2 > 0.f) bb2 |= m;
      if (v3 > 0.f) bb3 |= m;
    }
  }
  uint32_t* pw = P2 + n * PIMG + (h + 1) * PRS + (w4 * 4 + 1);
  pw[0] = bb0; pw[1] = bb1; pw[2] = bb2; pw[3] = bb3;
}

// ================ K5: out = A2*Y2 + B2 + (A1*Y1 + B1 + x)  (no conv) ==============
__global__ __launch_bounds__(256, 2) void bnout(const short* __restrict__ Y1,
    const short* __restrict__ Y2, const float* __restrict__ x,
    const float* __restrict__ SC, const StatLine* __restrict__ SB,
    const float* __restrict__ g1v, const float* __restrict__ b1v,
    const float* __restrict__ g2v, const float* __restrict__ b2v,
    float* __restrict__ out)
{
  __shared__ float A1s[32], B1s[32], A2s[32], B2s[32];
  const int tid = threadIdx.x;
  if (tid < 32) {
    bn_affine(SC, SB, g1v, b1v, tid, A1s[tid], B1s[tid]);
    bn_affine(SC + 1, SB + 32, g2v, b2v, tid, A2s[tid], B2s[tid]);
  }
  __syncthreads();

  int g = blockIdx.x * 256 + tid;
  int w4 = g % 40;
  int t1 = g / 40;
  int h = t1 % 160;
  int n = t1 / 160;
  int i = h * WW + w4 * 4;
  size_t pbase = (size_t)n * CH * HWL + i;

  #pragma unroll
  for (int cg = 0; cg < 4; ++cg) {
    float4 xv[8];
    short4 y1v[8], y2v[8];
    #pragma unroll
    for (int j = 0; j < 8; ++j) {
      size_t idx = pbase + (size_t)(cg * 8 + j) * HWL;
      xv[j]  = *reinterpret_cast<const float4*>(x + idx);
      y1v[j] = *reinterpret_cast<const short4*>(Y1 + idx);
      y2v[j] = *reinterpret_cast<const short4*>(Y2 + idx);
    }
    #pragma unroll
    for (int j = 0; j < 8; ++j) {
      int co = cg * 8 + j;
      float A1 = A1s[co], B1 = B1s[co], A2 = A2s[co], B2 = B2s[co];
      float v0 = fmaf(A1, (float)y1v[j].x, B1) + xv[j].x;   // inner, exact fp32
      float v1 = fmaf(A1, (float)y1v[j].y, B1) + xv[j].y;
      float v2 = fmaf(A1, (float)y1v[j].z, B1) + xv[j].z;
      float v3 = fmaf(A1, (float)y1v[j].w, B1) + xv[j].w;
      float4 o;
      o.x = fmaf(A2, (float)y2v[j].x, B2) + v0;
      o.y = fmaf(A2, (float)y2v[j].y, B2) + v1;
      o.z = fmaf(A2, (float)y2v[j].z, B2) + v2;
      o.w = fmaf(A2, (float)y2v[j].w, B2) + v3;
      *reinterpret_cast<float4*>(out + pbase + (size_t)co * HWL) = o;
    }
  }
}

extern "C" void kernel_launch(void* const* d_in, const int* in_sizes, int n_in,
                              void* d_out, int out_size, void* d_ws, size_t ws_size,
                              hipStream_t stream)
{
  (void)in_sizes; (void)n_in; (void)out_size; (void)ws_size;
  const float* x  = (const float*)d_in[0];
  const float* w1 = (const float*)d_in[1];
  const float* g1 = (const float*)d_in[2];
  const float* b1 = (const float*)d_in[3];
  const float* w2 = (const float*)d_in[4];
  const float* g2 = (const float*)d_in[5];
  const float* b2 = (const float*)d_in[6];
  float* out = (float*)d_out;
  char* ws = (char*)d_ws;

  uint32_t* P    = (uint32_t*)(ws + OFF_P);
  uint32_t* P2   = (uint32_t*)(ws + OFF_P2);
  short*    Y1   = (short*)(ws + OFF_Y1);
  short*    Y2   = (short*)(ws + OFF_Y2);
  uint32_t* WP   = (uint32_t*)(ws + OFF_WP);
  int*      CORR = (int*)(ws + OFF_CORR);
  float*    SC   = (float*)(ws + OFF_SC);
  StatLine* SB   = (StatLine*)(ws + OFF_SB);

  pack_prep<<<3443, 256, 0, stream>>>(x, w1, w2, P, P2, WP, CORR, SC, SB);
  conv_stats_y<<<800, 256, 0, stream>>>(P, WP, CORR, Y1, SB);
  bits2<<<800, 256, 0, stream>>>(Y1, x, SC, SB, g1, b1, P2);
  conv_stats_y<<<800, 256, 0, stream>>>(P2, WP + 288, CORR + 288, Y2, SB + 32);
  bnout<<<800, 256, 0, stream>>>(Y1, Y2, x, SC, SB, g1, b1, g2, b2, out);
}

// Round 13
// 201.538 us; speedup vs baseline: 1.0311x; 1.0311x over previous
//
#include <hip/hip_runtime.h>
#include <stdint.h>

#define NIMG 32
#define CH 32
#define HH 160
#define WW 160
#define HWL (HH*WW)            // 25600
#define PRS 164                // padded row stride (words)
#define PHH 162
#define PIMG (PHH*PRS)         // 26568 words per padded image
#define NPIX (NIMG*HWL)        // 819200 pixels
#define HALO_WORDS 968         // per image: 2*164 + 160*4

// workspace layout (bytes)
#define OFF_P     0
#define OFF_P2    3400704                    // P : 32*26568*4
#define OFF_IT    (OFF_P2 + 3400704)         // P2: same
#define OFF_WP    (OFF_IT + 52428800)        // innerT: bf16 [pixel][32]
#define OFF_CORR  (OFF_WP + 2304)
#define OFF_SC    (OFF_CORR + 2304)
#define OFF_SB    (OFF_SC + 128)             // 64 StatLines x 128 B

struct StatLine {                            // one 128B line per channel
  int s1; int pad0; unsigned long long s2; char pad[112];
};

#define AS1 __attribute__((address_space(1)))
#define AS3 __attribute__((address_space(3)))
__device__ __forceinline__ void dma16(const void* g, void* l) {
  __builtin_amdgcn_global_load_lds((const AS1 void*)g, (AS3 void*)l, 16, 0, 0);
}

__device__ __forceinline__ unsigned short f2bf(float f) {   // RNE float->bf16
  unsigned u = __float_as_uint(f);
  u += 0x7fffu + ((u >> 16) & 1u);
  return (unsigned short)(u >> 16);
}
__device__ __forceinline__ float bf2f(unsigned short u) {
  return __uint_as_float((uint32_t)u << 16);
}

__device__ __forceinline__ void conv4(const uint32_t r[3][6], const uint32_t* wsh,
                                      int co, int& a0, int& a1, int& a2, int& a3)
{
  a0 = a1 = a2 = a3 = 0;
  #pragma unroll
  for (int dy = 0; dy < 3; ++dy) {
    #pragma unroll
    for (int dx = 0; dx < 3; ++dx) {
      uint32_t wvv = wsh[co * 9 + dy * 3 + dx];
      a0 += __popc(r[dy][0 + dx] ^ wvv);
      a1 += __popc(r[dy][1 + dx] ^ wvv);
      a2 += __popc(r[dy][2 + dx] ^ wvv);
      a3 += __popc(r[dy][3 + dx] ^ wvv);
    }
  }
}

__device__ __forceinline__ void bn_affine(const float* SCp, const StatLine* sb,
    const float* gamma, const float* beta, int c, float& A, float& B)
{
  double sc = (double)SCp[0];
  double m  = sc * (double)sb[c].s1 / (double)NPIX;
  double ms = sc * sc * (double)(long long)sb[c].s2 / (double)NPIX;
  float inv = (float)(1.0 / sqrt(ms - m * m + 1e-5));
  float gm = gamma[c];
  A = gm * inv * (float)sc;
  B = beta[c] - gm * inv * (float)m;
}

// ================ K1: pack x via LDS DMA staging (256px tile) + prep + halo zero ====
__global__ __launch_bounds__(256) void pack_prep(const float* __restrict__ x,
    const float* __restrict__ w1, const float* __restrict__ w2,
    uint32_t* __restrict__ P, uint32_t* __restrict__ P2, uint32_t* __restrict__ WP,
    int* __restrict__ CORR, float* __restrict__ SC, StatLine* __restrict__ SB)
{
  __shared__ float lds[8192];                // 32 KB
  const int tid = threadIdx.x;
  const int b = blockIdx.x;

  if (b >= 3200) {
    if (b == 3442) {
      int* z = (int*)SB;
      for (int i = tid; i < 2048; i += 256) z[i] = 0;
      float* red = lds;
      uint32_t* wpl = (uint32_t*)(lds + 256);
      for (int cv = 0; cv < 2; ++cv) {
        const float* w = cv ? w2 : w1;
        float s = 0.f;
        #pragma unroll
        for (int j = 0; j < 9; ++j) {
          float4 v = *reinterpret_cast<const float4*>(w + (j * 256 + tid) * 4);
          s += fabsf(v.x) + fabsf(v.y) + fabsf(v.z) + fabsf(v.w);
        }
        red[tid] = s;
        __syncthreads();
        for (int st = 128; st > 0; st >>= 1) {
          if (tid < st) red[tid] += red[tid + st];
          __syncthreads();
        }
        if (tid == 0) SC[cv] = red[0] / 9216.0f;
        for (int i = tid; i < 288; i += 256) {
          int co = i / 9, t = i - co * 9;
          uint32_t bw = 0;
          for (int ci = 0; ci < 32; ++ci)
            bw |= (w[(co * 32 + ci) * 9 + t] > 0.0f) ? (1u << ci) : 0u;
          WP[cv * 288 + i] = bw;
          wpl[i] = bw;
        }
        __syncthreads();
        for (int i = tid; i < 288; i += 256) {
          int cls = i / 32, co = i - cls * 32;
          int hc = cls / 3, wc = cls - hc * 3;
          int corr = 0;
          for (int t = 0; t < 9; ++t) {
            int dy = t / 3 - 1, dx = t % 3 - 1;
            bool inval = (hc == 0 && dy == -1) || (hc == 2 && dy == 1) ||
                         (wc == 0 && dx == -1) || (wc == 2 && dx == 1);
            if (inval) corr += 32 - 2 * __popc(wpl[co * 9 + t]);
          }
          CORR[cv * 288 + cls * 32 + co] = corr;
        }
        __syncthreads();
      }
    } else {
      int k = (b - 3200) * 256 + tid;
      uint32_t* buf = (k < 32 * HALO_WORDS) ? P : P2;
      int j = k % (32 * HALO_WORDS);
      int img = j / HALO_WORDS;
      int r = j - img * HALO_WORDS;
      int pr, pc;
      if (r < 164)      { pr = 0;   pc = r; }
      else if (r < 328) { pr = 161; pc = r - 164; }
      else {
        int k2 = r - 328;
        pr = 1 + (k2 >> 2);
        int q = k2 & 3;
        pc = (q == 0) ? 0 : (160 + q);
      }
      buf[img * PIMG + pr * PRS + pc] = 0;
    }
    return;
  }

  int n = b / 100;
  int p0 = (b - n * 100) * 256;
  const float* xb = x + (size_t)n * CH * HWL + p0;
  #pragma unroll
  for (int it = 0; it < 8; ++it) {
    int c = it * 4 + (tid >> 6);
    dma16(xb + (size_t)c * HWL + (tid & 63) * 4, lds + c * 256);
  }
  __syncthreads();

  uint32_t bits = 0;
  #pragma unroll
  for (int c = 0; c < 32; ++c) {
    if (lds[c * 256 + tid] > 0.f) bits |= 1u << c;
  }
  int px = p0 + tid;
  int h = px / WW, w = px - h * WW;
  P[n * PIMG + (h + 1) * PRS + (w + 1)] = bits;
}

// ================ K2/K4: conv (recompute) -> per-channel stats only ================
__global__ __launch_bounds__(256) void conv_stats(const uint32_t* __restrict__ P,
    const uint32_t* __restrict__ WP, const int* __restrict__ CORR,
    StatLine* __restrict__ sb)
{
  __shared__ uint32_t wsh[288];
  __shared__ int csh[288];
  __shared__ int ls1[32], ls2[32];
  const int tid = threadIdx.x;
  for (int i = tid; i < 288; i += 256) { wsh[i] = WP[i]; csh[i] = CORR[i]; }
  if (tid < 32) { ls1[tid] = 0; ls2[tid] = 0; }
  __syncthreads();

  int g = blockIdx.x * 256 + tid;
  int w4 = g % 40;
  int t1 = g / 40;
  int h = t1 % 160;
  int n = t1 / 160;

  const uint32_t* base = P + n * PIMG + h * PRS + w4 * 4;
  uint32_t r[3][6];
  #pragma unroll
  for (int dy = 0; dy < 3; ++dy) {
    uint4 a = *reinterpret_cast<const uint4*>(base + dy * PRS);
    uint2 bw = *reinterpret_cast<const uint2*>(base + dy * PRS + 4);
    r[dy][0] = a.x; r[dy][1] = a.y; r[dy][2] = a.z; r[dy][3] = a.w;
    r[dy][4] = bw.x; r[dy][5] = bw.y;
  }

  int rowc = (h == 0) ? 0 : ((h == 159) ? 6 : 3);
  int cls0  = rowc + ((w4 == 0) ? 0 : 1);
  int cls12 = rowc + 1;
  int cls3  = rowc + ((w4 == 39) ? 2 : 1);
  int lane = tid & 63;

  #pragma unroll
  for (int co = 0; co < 32; ++co) {
    int a0, a1, a2, a3;
    conv4(r, wsh, co, a0, a1, a2, a3);
    int d0 = 288 - 2 * a0 - csh[cls0 * 32 + co];
    int d1 = 288 - 2 * a1 - csh[cls12 * 32 + co];
    int d2 = 288 - 2 * a2 - csh[cls12 * 32 + co];
    int d3 = 288 - 2 * a3 - csh[cls3 * 32 + co];
    int ds = d0 + d1 + d2 + d3;
    int sq = d0 * d0 + d1 * d1 + d2 * d2 + d3 * d3;
    #pragma unroll
    for (int off = 32; off > 0; off >>= 1) {
      ds += __shfl_down(ds, off);
      sq += __shfl_down(sq, off);
    }
    if (lane == 0) { atomicAdd(&ls1[co], ds); atomicAdd(&ls2[co], sq); }
  }
  __syncthreads();
  if (tid < 32) {
    atomicAdd(&sb[tid].s1, ls1[tid]);
    atomicAdd(&sb[tid].s2, (unsigned long long)(long long)ls2[tid]);
  }
}

// ================ K3: conv1 + BN1 + residual(x via 32KB DMA tile) ==================
// 1 px/thread, 3200 blocks; writes P2 bits + innerT bf16 [pixel][32] (64B contiguous)
__global__ __launch_bounds__(256) void conv_bn1(const uint32_t* __restrict__ P,
    const uint32_t* __restrict__ WP, const int* __restrict__ CORR,
    const float* __restrict__ x, const float* __restrict__ SCp,
    const StatLine* __restrict__ sb, const float* __restrict__ gamma,
    const float* __restrict__ beta, unsigned short* __restrict__ IT,
    uint32_t* __restrict__ P2)
{
  __shared__ float xs[8192];                 // 32 KB x tile [c][256]
  __shared__ uint32_t wsh[288];
  __shared__ int csh[288];
  __shared__ float Ash[32], Bsh[32];
  const int tid = threadIdx.x;
  const int b = blockIdx.x;
  int n = b / 100;
  int p0 = (b - n * 100) * 256;
  const float* xb = x + (size_t)n * CH * HWL + p0;

  #pragma unroll
  for (int it = 0; it < 8; ++it) {
    int c = it * 4 + (tid >> 6);
    dma16(xb + (size_t)c * HWL + (tid & 63) * 4, xs + c * 256);
  }

  for (int i = tid; i < 288; i += 256) { wsh[i] = WP[i]; csh[i] = CORR[i]; }
  if (tid < 32) bn_affine(SCp, sb, gamma, beta, tid, Ash[tid], Bsh[tid]);

  int px = p0 + tid;
  int h = px / WW, w = px - h * WW;
  const uint32_t* bp = P + n * PIMG + h * PRS + w;   // padded rows h..h+2, cols w..w+2
  uint32_t r9[3][3];
  #pragma unroll
  for (int dy = 0; dy < 3; ++dy) {
    r9[dy][0] = bp[dy * PRS + 0];
    r9[dy][1] = bp[dy * PRS + 1];
    r9[dy][2] = bp[dy * PRS + 2];
  }
  int hc = (h == 0) ? 0 : ((h == 159) ? 2 : 1);
  int wc = (w == 0) ? 0 : ((w == 159) ? 2 : 1);
  int cls = hc * 3 + wc;

  __syncthreads();                            // DMA drained; tables ready

  uint32_t bits = 0;
  uint32_t ow[16];                            // 32 bf16 packed
  #pragma unroll
  for (int co = 0; co < 32; ++co) {
    int a = 0;
    #pragma unroll
    for (int dy = 0; dy < 3; ++dy) {
      #pragma unroll
      for (int dx = 0; dx < 3; ++dx)
        a += __popc(r9[dy][dx] ^ wsh[co * 9 + dy * 3 + dx]);
    }
    int d = 288 - 2 * a - csh[cls * 32 + co];
    float v = fmaf(Ash[co], (float)d, Bsh[co]) + xs[co * 256 + tid];
    if (v > 0.f) bits |= 1u << co;
    uint32_t bf = (uint32_t)f2bf(v);
    if ((co & 1) == 0) ow[co >> 1] = bf;
    else               ow[co >> 1] |= bf << 16;
  }
  P2[n * PIMG + (h + 1) * PRS + (w + 1)] = bits;
  uint4* ip = (uint4*)(IT + (size_t)(n * HWL + px) * 32);
  ip[0] = make_uint4(ow[0], ow[1], ow[2], ow[3]);
  ip[1] = make_uint4(ow[4], ow[5], ow[6], ow[7]);
  ip[2] = make_uint4(ow[8], ow[9], ow[10], ow[11]);
  ip[3] = make_uint4(ow[12], ow[13], ow[14], ow[15]);
}

// ================ K5: conv2 + BN2 + residual(innerT contiguous) -> out fp32 ========
// 4 px/thread, 800 blocks; innerT read = 256B contiguous per thread, no gather
__global__ __launch_bounds__(256, 2) void conv_bn2(const uint32_t* __restrict__ P2,
    const uint32_t* __restrict__ WP, const int* __restrict__ CORR,
    const unsigned short* __restrict__ IT, const float* __restrict__ SCp,
    const StatLine* __restrict__ sb, const float* __restrict__ gamma,
    const float* __restrict__ beta, float* __restrict__ out)
{
  __shared__ uint32_t wsh[288];
  __shared__ int csh[288];
  __shared__ float Ash[32], Bsh[32];
  const int tid = threadIdx.x;
  for (int i = tid; i < 288; i += 256) { wsh[i] = WP[i]; csh[i] = CORR[i]; }
  if (tid < 32) bn_affine(SCp, sb, gamma, beta, tid, Ash[tid], Bsh[tid]);
  __syncthreads();

  int g = blockIdx.x * 256 + tid;
  int w4 = g % 40;
  int t1 = g / 40;
  int h = t1 % 160;
  int n = t1 / 160;

  const uint32_t* base = P2 + n * PIMG + h * PRS + w4 * 4;
  uint32_t r[3][6];
  #pragma unroll
  for (int dy = 0; dy < 3; ++dy) {
    uint4 a = *reinterpret_cast<const uint4*>(base + dy * PRS);
    uint2 bw = *reinterpret_cast<const uint2*>(base + dy * PRS + 4);
    r[dy][0] = a.x; r[dy][1] = a.y; r[dy][2] = a.z; r[dy][3] = a.w;
    r[dy][4] = bw.x; r[dy][5] = bw.y;
  }
  int rowc = (h == 0) ? 0 : ((h == 159) ? 6 : 3);
  int cls0  = rowc + ((w4 == 0) ? 0 : 1);
  int cls12 = rowc + 1;
  int cls3  = rowc + ((w4 == 39) ? 2 : 1);

  int i = h * WW + w4 * 4;
  size_t pbase = (size_t)n * CH * HWL + i;

  // innerT for 4 pixels: 256B contiguous, 16 dwordx4 off one base
  uint4 tt[16];
  const uint4* ip = (const uint4*)(IT + (size_t)(n * HWL + i) * 32);
  #pragma unroll
  for (int q = 0; q < 16; ++q) tt[q] = ip[q];

  #pragma unroll
  for (int co = 0; co < 32; ++co) {
    int e0, e1, e2, e3;
    conv4(r, wsh, co, e0, e1, e2, e3);
    int f0 = 288 - 2 * e0 - csh[cls0 * 32 + co];
    int f1 = 288 - 2 * e1 - csh[cls12 * 32 + co];
    int f2 = 288 - 2 * e2 - csh[cls12 * 32 + co];
    int f3 = 288 - 2 * e3 - csh[cls3 * 32 + co];
    float A = Ash[co], Bv = Bsh[co];
    // inner for pixel p at word tt[p*4 + (co>>3)], 32b sel (co>>1)&3, half co&1
    const int qw = co >> 3;
    const int ws = (co >> 1) & 3;
    const int hf = co & 1;
    uint32_t u0 = (ws == 0) ? tt[0 * 4 + qw].x : (ws == 1) ? tt[0 * 4 + qw].y
                : (ws == 2) ? tt[0 * 4 + qw].z : tt[0 * 4 + qw].w;
    uint32_t u1 = (ws == 0) ? tt[1 * 4 + qw].x : (ws == 1) ? tt[1 * 4 + qw].y
                : (ws == 2) ? tt[1 * 4 + qw].z : tt[1 * 4 + qw].w;
    uint32_t u2 = (ws == 0) ? tt[2 * 4 + qw].x : (ws == 1) ? tt[2 * 4 + qw].y
                : (ws == 2) ? tt[2 * 4 + qw].z : tt[2 * 4 + qw].w;
    uint32_t u3 = (ws == 0) ? tt[3 * 4 + qw].x : (ws == 1) ? tt[3 * 4 + qw].y
                : (ws == 2) ? tt[3 * 4 + qw].z : tt[3 * 4 + qw].w;
    float i0 = bf2f((unsigned short)(hf ? (u0 >> 16) : (u0 & 0xffff)));
    float i1 = bf2f((unsigned short)(hf ? (u1 >> 16) : (u1 & 0xffff)));
    float i2 = bf2f((unsigned short)(hf ? (u2 >> 16) : (u2 & 0xffff)));
    float i3 = bf2f((unsigned short)(hf ? (u3 >> 16) : (u3 & 0xffff)));
    float4 o;
    o.x = fmaf(A, (float)f0, Bv) + i0;
    o.y = fmaf(A, (float)f1, Bv) + i1;
    o.z = fmaf(A, (float)f2, Bv) + i2;
    o.w = fmaf(A, (float)f3, Bv) + i3;
    *reinterpret_cast<float4*>(out + pbase + (size_t)co * HWL) = o;
  }
}

extern "C" void kernel_launch(void* const* d_in, const int* in_sizes, int n_in,
                              void* d_out, int out_size, void* d_ws, size_t ws_size,
                              hipStream_t stream)
{
  (void)in_sizes; (void)n_in; (void)out_size; (void)ws_size;
  const float* x  = (const float*)d_in[0];
  const float* w1 = (const float*)d_in[1];
  const float* g1 = (const float*)d_in[2];
  const float* b1 = (const float*)d_in[3];
  const float* w2 = (const float*)d_in[4];
  const float* g2 = (const float*)d_in[5];
  const float* b2 = (const float*)d_in[6];
  float* out = (float*)d_out;
  char* ws = (char*)d_ws;

  uint32_t*       P    = (uint32_t*)(ws + OFF_P);
  uint32_t*       P2   = (uint32_t*)(ws + OFF_P2);
  unsigned short* IT   = (unsigned short*)(ws + OFF_IT);
  uint32_t*       WP   = (uint32_t*)(ws + OFF_WP);
  int*            CORR = (int*)(ws + OFF_CORR);
  float*          SC   = (float*)(ws + OFF_SC);
  StatLine*       SB   = (StatLine*)(ws + OFF_SB);

  pack_prep<<<3443, 256, 0, stream>>>(x, w1, w2, P, P2, WP, CORR, SC, SB);
  conv_stats<<<800, 256, 0, stream>>>(P, WP, CORR, SB);
  conv_bn1<<<3200, 256, 0, stream>>>(P, WP, CORR, x, SC, SB, g1, b1, IT, P2);
  conv_stats<<<800, 256, 0, stream>>>(P2, WP + 288, CORR + 288, SB + 32);
  conv_bn2<<<800, 256, 0, stream>>>(P2, WP + 288, CORR + 288, IT, SC + 1, SB + 32, g2, b2, out);
}

// Round 14
// 181.114 us; speedup vs baseline: 1.1474x; 1.1128x over previous
//
#include <hip/hip_runtime.h>
#include <stdint.h>

#define NIMG 32
#define CH 32
#define HH 160
#define WW 160
#define HWL (HH*WW)            // 25600
#define PRS 164                // padded row stride (words)
#define PHH 162
#define PIMG (PHH*PRS)         // 26568 words per padded image
#define NPIX (NIMG*HWL)        // 819200 pixels
#define HALO_WORDS 968         // per image: 2*164 + 160*4

// workspace layout (bytes)
#define OFF_P     0
#define OFF_P2    3400704                    // P : 32*26568*4
#define OFF_IN    (OFF_P2 + 3400704)         // P2: same
#define OFF_WP    (OFF_IN + 52428800)        // inner: bf16 plane-major
#define OFF_CORR  (OFF_WP + 2304)
#define OFF_SC    (OFF_CORR + 2304)
#define OFF_SB    (OFF_SC + 128)             // 64 StatLines x 128 B

struct StatLine {                            // one 128B line per channel
  int s1; int pad0; unsigned long long s2; char pad[112];
};

#define AS1 __attribute__((address_space(1)))
#define AS3 __attribute__((address_space(3)))
__device__ __forceinline__ void dma16(const void* g, void* l) {
  __builtin_amdgcn_global_load_lds((const AS1 void*)g, (AS3 void*)l, 16, 0, 0);
}

__device__ __forceinline__ unsigned short f2bf(float f) {   // RNE float->bf16
  unsigned u = __float_as_uint(f);
  u += 0x7fffu + ((u >> 16) & 1u);
  return (unsigned short)(u >> 16);
}
__device__ __forceinline__ float bf2f(unsigned short u) {
  return __uint_as_float((uint32_t)u << 16);
}

__device__ __forceinline__ void conv4(const uint32_t r[3][6], const uint32_t* wsh,
                                      int co, int& a0, int& a1, int& a2, int& a3)
{
  a0 = a1 = a2 = a3 = 0;
  #pragma unroll
  for (int dy = 0; dy < 3; ++dy) {
    #pragma unroll
    for (int dx = 0; dx < 3; ++dx) {
      uint32_t wvv = wsh[co * 9 + dy * 3 + dx];
      a0 += __popc(r[dy][0 + dx] ^ wvv);
      a1 += __popc(r[dy][1 + dx] ^ wvv);
      a2 += __popc(r[dy][2 + dx] ^ wvv);
      a3 += __popc(r[dy][3 + dx] ^ wvv);
    }
  }
}

__device__ __forceinline__ void conv2(const uint32_t r[3][4], const uint32_t* wsh,
                                      int co, int& a0, int& a1)
{
  a0 = a1 = 0;
  #pragma unroll
  for (int dy = 0; dy < 3; ++dy) {
    #pragma unroll
    for (int dx = 0; dx < 3; ++dx) {
      uint32_t wvv = wsh[co * 9 + dy * 3 + dx];
      a0 += __popc(r[dy][dx] ^ wvv);
      a1 += __popc(r[dy][dx + 1] ^ wvv);
    }
  }
}

__device__ __forceinline__ void bn_affine(const float* SCp, const StatLine* sb,
    const float* gamma, const float* beta, int c, float& A, float& B)
{
  double sc = (double)SCp[0];
  double m  = sc * (double)sb[c].s1 / (double)NPIX;
  double ms = sc * sc * (double)(long long)sb[c].s2 / (double)NPIX;
  float inv = (float)(1.0 / sqrt(ms - m * m + 1e-5));
  float gm = gamma[c];
  A = gm * inv * (float)sc;
  B = beta[c] - gm * inv * (float)m;
}

// ================ K1: pack x via LDS DMA staging (256px tile) + prep + halo zero ====
__global__ __launch_bounds__(256) void pack_prep(const float* __restrict__ x,
    const float* __restrict__ w1, const float* __restrict__ w2,
    uint32_t* __restrict__ P, uint32_t* __restrict__ P2, uint32_t* __restrict__ WP,
    int* __restrict__ CORR, float* __restrict__ SC, StatLine* __restrict__ SB)
{
  __shared__ float lds[8192];                // 32 KB
  const int tid = threadIdx.x;
  const int b = blockIdx.x;

  if (b >= 3200) {
    if (b == 3442) {
      int* z = (int*)SB;
      for (int i = tid; i < 2048; i += 256) z[i] = 0;
      float* red = lds;
      uint32_t* wpl = (uint32_t*)(lds + 256);
      for (int cv = 0; cv < 2; ++cv) {
        const float* w = cv ? w2 : w1;
        float s = 0.f;
        #pragma unroll
        for (int j = 0; j < 9; ++j) {
          float4 v = *reinterpret_cast<const float4*>(w + (j * 256 + tid) * 4);
          s += fabsf(v.x) + fabsf(v.y) + fabsf(v.z) + fabsf(v.w);
        }
        red[tid] = s;
        __syncthreads();
        for (int st = 128; st > 0; st >>= 1) {
          if (tid < st) red[tid] += red[tid + st];
          __syncthreads();
        }
        if (tid == 0) SC[cv] = red[0] / 9216.0f;
        for (int i = tid; i < 288; i += 256) {
          int co = i / 9, t = i - co * 9;
          uint32_t bw = 0;
          for (int ci = 0; ci < 32; ++ci)
            bw |= (w[(co * 32 + ci) * 9 + t] > 0.0f) ? (1u << ci) : 0u;
          WP[cv * 288 + i] = bw;
          wpl[i] = bw;
        }
        __syncthreads();
        for (int i = tid; i < 288; i += 256) {
          int cls = i / 32, co = i - cls * 32;
          int hc = cls / 3, wc = cls - hc * 3;
          int corr = 0;
          for (int t = 0; t < 9; ++t) {
            int dy = t / 3 - 1, dx = t % 3 - 1;
            bool inval = (hc == 0 && dy == -1) || (hc == 2 && dy == 1) ||
                         (wc == 0 && dx == -1) || (wc == 2 && dx == 1);
            if (inval) corr += 32 - 2 * __popc(wpl[co * 9 + t]);
          }
          CORR[cv * 288 + cls * 32 + co] = corr;
        }
        __syncthreads();
      }
    } else {
      int k = (b - 3200) * 256 + tid;
      uint32_t* buf = (k < 32 * HALO_WORDS) ? P : P2;
      int j = k % (32 * HALO_WORDS);
      int img = j / HALO_WORDS;
      int r = j - img * HALO_WORDS;
      int pr, pc;
      if (r < 164)      { pr = 0;   pc = r; }
      else if (r < 328) { pr = 161; pc = r - 164; }
      else {
        int k2 = r - 328;
        pr = 1 + (k2 >> 2);
        int q = k2 & 3;
        pc = (q == 0) ? 0 : (160 + q);
      }
      buf[img * PIMG + pr * PRS + pc] = 0;
    }
    return;
  }

  int n = b / 100;
  int p0 = (b - n * 100) * 256;
  const float* xb = x + (size_t)n * CH * HWL + p0;
  #pragma unroll
  for (int it = 0; it < 8; ++it) {
    int c = it * 4 + (tid >> 6);
    dma16(xb + (size_t)c * HWL + (tid & 63) * 4, lds + c * 256);
  }
  __syncthreads();

  uint32_t bits = 0;
  #pragma unroll
  for (int c = 0; c < 32; ++c) {
    if (lds[c * 256 + tid] > 0.f) bits |= 1u << c;
  }
  int px = p0 + tid;
  int h = px / WW, w = px - h * WW;
  P[n * PIMG + (h + 1) * PRS + (w + 1)] = bits;
}

// ================ K2/K4: conv (recompute) -> per-channel stats only ================
__global__ __launch_bounds__(256) void conv_stats(const uint32_t* __restrict__ P,
    const uint32_t* __restrict__ WP, const int* __restrict__ CORR,
    StatLine* __restrict__ sb)
{
  __shared__ uint32_t wsh[288];
  __shared__ int csh[288];
  __shared__ int ls1[32], ls2[32];
  const int tid = threadIdx.x;
  for (int i = tid; i < 288; i += 256) { wsh[i] = WP[i]; csh[i] = CORR[i]; }
  if (tid < 32) { ls1[tid] = 0; ls2[tid] = 0; }
  __syncthreads();

  int g = blockIdx.x * 256 + tid;
  int w4 = g % 40;
  int t1 = g / 40;
  int h = t1 % 160;
  int n = t1 / 160;

  const uint32_t* base = P + n * PIMG + h * PRS + w4 * 4;
  uint32_t r[3][6];
  #pragma unroll
  for (int dy = 0; dy < 3; ++dy) {
    uint4 a = *reinterpret_cast<const uint4*>(base + dy * PRS);
    uint2 bw = *reinterpret_cast<const uint2*>(base + dy * PRS + 4);
    r[dy][0] = a.x; r[dy][1] = a.y; r[dy][2] = a.z; r[dy][3] = a.w;
    r[dy][4] = bw.x; r[dy][5] = bw.y;
  }

  int rowc = (h == 0) ? 0 : ((h == 159) ? 6 : 3);
  int cls0  = rowc + ((w4 == 0) ? 0 : 1);
  int cls12 = rowc + 1;
  int cls3  = rowc + ((w4 == 39) ? 2 : 1);
  int lane = tid & 63;

  #pragma unroll
  for (int co = 0; co < 32; ++co) {
    int a0, a1, a2, a3;
    conv4(r, wsh, co, a0, a1, a2, a3);
    int d0 = 288 - 2 * a0 - csh[cls0 * 32 + co];
    int d1 = 288 - 2 * a1 - csh[cls12 * 32 + co];
    int d2 = 288 - 2 * a2 - csh[cls12 * 32 + co];
    int d3 = 288 - 2 * a3 - csh[cls3 * 32 + co];
    int ds = d0 + d1 + d2 + d3;
    int sq = d0 * d0 + d1 * d1 + d2 * d2 + d3 * d3;
    #pragma unroll
    for (int off = 32; off > 0; off >>= 1) {
      ds += __shfl_down(ds, off);
      sq += __shfl_down(sq, off);
    }
    if (lane == 0) { atomicAdd(&ls1[co], ds); atomicAdd(&ls2[co], sq); }
  }
  __syncthreads();
  if (tid < 32) {
    atomicAdd(&sb[tid].s1, ls1[tid]);
    atomicAdd(&sb[tid].s2, (unsigned long long)(long long)ls2[tid]);
  }
}

// ================ K3: conv1 + BN1 + residual(x via 2x32KB DMA chunks) ==============
// 512-px tile, 2 px/thread, 1600 blocks; coalesced uint2 bit reads;
// writes inner (bf16 plane-major) + P2 bits
__global__ __launch_bounds__(256) void conv_bn1(const uint32_t* __restrict__ P,
    const uint32_t* __restrict__ WP, const int* __restrict__ CORR,
    const float* __restrict__ x, const float* __restrict__ SCp,
    const StatLine* __restrict__ sb, const float* __restrict__ gamma,
    const float* __restrict__ beta, unsigned short* __restrict__ IN,
    uint32_t* __restrict__ P2)
{
  __shared__ float xs[8192];                 // 32 KB: 16 channels x 512 px
  __shared__ uint32_t wsh[288];
  __shared__ int csh[288];
  __shared__ float Ash[32], Bsh[32];
  const int tid = threadIdx.x;
  const int b = blockIdx.x;
  int n = b / 50;
  int p0 = (b - n * 50) * 512;
  const float* xb = x + (size_t)n * CH * HWL + p0;

  // DMA chunk 0: channels 0..15 (32 half-channel segments of 1 KB)
  #pragma unroll
  for (int it = 0; it < 8; ++it) {
    int q = it * 4 + (tid >> 6);
    int c = q >> 1, hf = q & 1;
    dma16(xb + (size_t)c * HWL + hf * 256 + (tid & 63) * 4,
          xs + c * 512 + hf * 256 + (tid & 63) * 4);
  }
  for (int i = tid; i < 288; i += 256) { wsh[i] = WP[i]; csh[i] = CORR[i]; }
  if (tid < 32) bn_affine(SCp, sb, gamma, beta, tid, Ash[tid], Bsh[tid]);

  int p = p0 + 2 * tid;
  int h = p / WW, wloc = p - h * WW;         // wloc even, pair never crosses rows
  const uint32_t* bp = P + n * PIMG + h * PRS + wloc;
  uint32_t r[3][4];
  #pragma unroll
  for (int dy = 0; dy < 3; ++dy) {
    uint2 u0 = *reinterpret_cast<const uint2*>(bp + dy * PRS);
    uint2 u1 = *reinterpret_cast<const uint2*>(bp + dy * PRS + 2);
    r[dy][0] = u0.x; r[dy][1] = u0.y; r[dy][2] = u1.x; r[dy][3] = u1.y;
  }
  int rowc = (h == 0) ? 0 : ((h == 159) ? 6 : 3);
  int cls0 = rowc + ((wloc == 0) ? 0 : 1);
  int cls1 = rowc + ((wloc == 158) ? 2 : 1);
  size_t ibase = (size_t)n * CH * HWL + p;

  __syncthreads();                            // chunk-0 DMA drained; tables ready

  uint32_t bb0 = 0, bb1 = 0;
  #pragma unroll
  for (int co = 0; co < 16; ++co) {
    int a0, a1;
    conv2(r, wsh, co, a0, a1);
    int d0 = 288 - 2 * a0 - csh[cls0 * 32 + co];
    int d1 = 288 - 2 * a1 - csh[cls1 * 32 + co];
    float2 xv = *reinterpret_cast<const float2*>(xs + co * 512 + 2 * tid);
    float v0 = fmaf(Ash[co], (float)d0, Bsh[co]) + xv.x;
    float v1 = fmaf(Ash[co], (float)d1, Bsh[co]) + xv.y;
    ushort2 o; o.x = f2bf(v0); o.y = f2bf(v1);
    *reinterpret_cast<ushort2*>(IN + ibase + (size_t)co * HWL) = o;
    if (v0 > 0.f) bb0 |= 1u << co;
    if (v1 > 0.f) bb1 |= 1u << co;
  }
  __syncthreads();                            // all chunk-0 reads done (WAR)

  // DMA chunk 1: channels 16..31
  #pragma unroll
  for (int it = 0; it < 8; ++it) {
    int q = it * 4 + (tid >> 6);
    int c = q >> 1, hf = q & 1;
    dma16(xb + (size_t)(16 + c) * HWL + hf * 256 + (tid & 63) * 4,
          xs + c * 512 + hf * 256 + (tid & 63) * 4);
  }
  __syncthreads();                            // chunk-1 drained

  #pragma unroll
  for (int co = 16; co < 32; ++co) {
    int a0, a1;
    conv2(r, wsh, co, a0, a1);
    int d0 = 288 - 2 * a0 - csh[cls0 * 32 + co];
    int d1 = 288 - 2 * a1 - csh[cls1 * 32 + co];
    float2 xv = *reinterpret_cast<const float2*>(xs + (co - 16) * 512 + 2 * tid);
    float v0 = fmaf(Ash[co], (float)d0, Bsh[co]) + xv.x;
    float v1 = fmaf(Ash[co], (float)d1, Bsh[co]) + xv.y;
    ushort2 o; o.x = f2bf(v0); o.y = f2bf(v1);
    *reinterpret_cast<ushort2*>(IN + ibase + (size_t)co * HWL) = o;
    if (v0 > 0.f) bb0 |= 1u << co;
    if (v1 > 0.f) bb1 |= 1u << co;
  }
  uint32_t* pw = P2 + n * PIMG + (h + 1) * PRS + (wloc + 1);
  pw[0] = bb0; pw[1] = bb1;
}

// ================ K5: conv2 + BN2 + residual(inner via 32KB DMA) -> out fp32 =======
// 512-px tile, 2 px/thread, 1600 blocks; inner bf16 tile = exactly 32 KB
__global__ __launch_bounds__(256) void conv_bn2(const uint32_t* __restrict__ P2,
    const uint32_t* __restrict__ WP, const int* __restrict__ CORR,
    const unsigned short* __restrict__ IN, const float* __restrict__ SCp,
    const StatLine* __restrict__ sb, const float* __restrict__ gamma,
    const float* __restrict__ beta, float* __restrict__ out)
{
  __shared__ unsigned short is[16384];       // 32 KB: 32 channels x 512 px bf16
  __shared__ uint32_t wsh[288];
  __shared__ int csh[288];
  __shared__ float Ash[32], Bsh[32];
  const int tid = threadIdx.x;
  const int b = blockIdx.x;
  int n = b / 50;
  int p0 = (b - n * 50) * 512;
  const unsigned short* ib = IN + (size_t)n * CH * HWL + p0;

  #pragma unroll
  for (int it = 0; it < 8; ++it) {
    int c = it * 4 + (tid >> 6);             // one 1 KB channel segment per wave-issue
    dma16(ib + (size_t)c * HWL + (tid & 63) * 8, is + c * 512 + (tid & 63) * 8);
  }
  for (int i = tid; i < 288; i += 256) { wsh[i] = WP[i]; csh[i] = CORR[i]; }
  if (tid < 32) bn_affine(SCp, sb, gamma, beta, tid, Ash[tid], Bsh[tid]);

  int p = p0 + 2 * tid;
  int h = p / WW, wloc = p - h * WW;
  const uint32_t* bp = P2 + n * PIMG + h * PRS + wloc;
  uint32_t r[3][4];
  #pragma unroll
  for (int dy = 0; dy < 3; ++dy) {
    uint2 u0 = *reinterpret_cast<const uint2*>(bp + dy * PRS);
    uint2 u1 = *reinterpret_cast<const uint2*>(bp + dy * PRS + 2);
    r[dy][0] = u0.x; r[dy][1] = u0.y; r[dy][2] = u1.x; r[dy][3] = u1.y;
  }
  int rowc = (h == 0) ? 0 : ((h == 159) ? 6 : 3);
  int cls0 = rowc + ((wloc == 0) ? 0 : 1);
  int cls1 = rowc + ((wloc == 158) ? 2 : 1);
  size_t obase = (size_t)n * CH * HWL + p;

  __syncthreads();                            // DMA drained; tables ready

  #pragma unroll
  for (int co = 0; co < 32; ++co) {
    int a0, a1;
    conv2(r, wsh, co, a0, a1);
    int f0 = 288 - 2 * a0 - csh[cls0 * 32 + co];
    int f1 = 288 - 2 * a1 - csh[cls1 * 32 + co];
    ushort2 iv = *reinterpret_cast<const ushort2*>(is + co * 512 + 2 * tid);
    float2 o;
    o.x = fmaf(Ash[co], (float)f0, Bsh[co]) + bf2f(iv.x);
    o.y = fmaf(Ash[co], (float)f1, Bsh[co]) + bf2f(iv.y);
    *reinterpret_cast<float2*>(out + obase + (size_t)co * HWL) = o;
  }
}

extern "C" void kernel_launch(void* const* d_in, const int* in_sizes, int n_in,
                              void* d_out, int out_size, void* d_ws, size_t ws_size,
                              hipStream_t stream)
{
  (void)in_sizes; (void)n_in; (void)out_size; (void)ws_size;
  const float* x  = (const float*)d_in[0];
  const float* w1 = (const float*)d_in[1];
  const float* g1 = (const float*)d_in[2];
  const float* b1 = (const float*)d_in[3];
  const float* w2 = (const float*)d_in[4];
  const float* g2 = (const float*)d_in[5];
  const float* b2 = (const float*)d_in[6];
  float* out = (float*)d_out;
  char* ws = (char*)d_ws;

  uint32_t*       P    = (uint32_t*)(ws + OFF_P);
  uint32_t*       P2   = (uint32_t*)(ws + OFF_P2);
  unsigned short* IN   = (unsigned short*)(ws + OFF_IN);
  uint32_t*       WP   = (uint32_t*)(ws + OFF_WP);
  int*            CORR = (int*)(ws + OFF_CORR);
  float*          SC   = (float*)(ws + OFF_SC);
  StatLine*       SB   = (StatLine*)(ws + OFF_SB);

  pack_prep<<<3443, 256, 0, stream>>>(x, w1, w2, P, P2, WP, CORR, SC, SB);
  conv_stats<<<800, 256, 0, stream>>>(P, WP, CORR, SB);
  conv_bn1<<<1600, 256, 0, stream>>>(P, WP, CORR, x, SC, SB, g1, b1, IN, P2);
  conv_stats<<<800, 256, 0, stream>>>(P2, WP + 288, CORR + 288, SB + 32);
  conv_bn2<<<1600, 256, 0, stream>>>(P2, WP + 288, CORR + 288, IN, SC + 1, SB + 32, g2, b2, out);
}